// Round 8
// baseline (520.385 us; speedup 1.0000x reference)
//
#include <hip/hip_runtime.h>
#include <hip/hip_bf16.h>
#include <cstdint>
#include <cstddef>

#define D_DIM 512
#define B_DIM 8
#define S_DIM 4096
#define M_DIM (B_DIM * S_DIM)   // 32768 tokens
#define CHUNK 64
#define NCHUNK (S_DIM / CHUNK)  // 64 chunks per batch
#define NSEG 8
#define CSEG (NCHUNK / NSEG)    // 8 chunks per segment
#define EPS_C 1e-6f

typedef __attribute__((ext_vector_type(8))) short bf16x8;
typedef __attribute__((ext_vector_type(4))) float f32x4;

#define GLOAD_LDS16(src, dst)                                              \
  __builtin_amdgcn_global_load_lds(                                        \
      (const __attribute__((address_space(1))) void*)(src),                \
      (__attribute__((address_space(3))) void*)(dst), 16, 0, 0)

__device__ __forceinline__ unsigned short f2bf(float f) {
  uint32_t u = __float_as_uint(f);
  u = (u + 0x7fffu + ((u >> 16) & 1u)) >> 16;   // RNE; inputs finite
  return (unsigned short)u;
}
__device__ __forceinline__ float bf2f(unsigned short s) { return __uint_as_float(((uint32_t)s) << 16); }

// ---------------- fp32 -> bf16 conversion ----------------
__global__ void cvt_f32_bf16(const float* __restrict__ in, unsigned short* __restrict__ out, int n4) {
  int i = blockIdx.x * blockDim.x + threadIdx.x;
  int stride = gridDim.x * blockDim.x;
  for (; i < n4; i += stride) {
    float4 f = ((const float4*)in)[i];
    ushort4 o;
    o.x = f2bf(f.x); o.y = f2bf(f.y); o.z = f2bf(f.z); o.w = f2bf(f.w);
    ((ushort4*)out)[i] = o;
  }
}

// ---------------- proj GEMM: 256x256 tile, BK=64, 2-phase single-barrier (R7) ------
#define PTM 256
#define PTN 256
#define PBK 64

__global__ __launch_bounds__(512, 2) void proj_gemm(
    const unsigned short* __restrict__ Xb,
    const unsigned short* __restrict__ Wb,
    const float* __restrict__ bq, const float* __restrict__ bk,
    const float* __restrict__ bv, const float* __restrict__ ba,
    unsigned short* __restrict__ q_ws, unsigned short* __restrict__ k_ws,
    unsigned short* __restrict__ v_ws, unsigned short* __restrict__ g_ws) {
  __shared__ unsigned short SB[2 * (PTM + PTN) * PBK];   // 128 KB

  const int proj = blockIdx.z;
  const unsigned short* W = Wb + (size_t)proj * D_DIM * D_DIM;
  const int m0 = blockIdx.x * PTM;
  const int n0 = blockIdx.y * PTN;
  const int lane = threadIdx.x & 63;
  const int w = threadIdx.x >> 6;
  const int l16 = lane & 15, q4 = lane >> 4;
  const int wm = (w >> 2) * 128;
  const int wn = (w & 3) * 64;

  f32x4 acc[8][4];
#pragma unroll
  for (int m = 0; m < 8; ++m)
#pragma unroll
    for (int n = 0; n < 4; ++n) acc[m][n] = (f32x4){0.f, 0.f, 0.f, 0.f};

  const int srow = lane >> 3;
  const int sg = lane & 7;

  auto STAGE = [&](int buf, int kc) {
    unsigned short* A = SB + buf * ((PTM + PTN) * PBK);
    unsigned short* Bs = A + PTM * PBK;
#pragma unroll
    for (int q = 0; q < 4; ++q) {
      const int row = w * 32 + q * 8 + srow;
      const int g = sg ^ (row & 7);
      GLOAD_LDS16(&Xb[(size_t)(m0 + row) * D_DIM + kc + g * 8], &A[(w * 32 + q * 8) * PBK]);
      GLOAD_LDS16(&W[(size_t)(n0 + row) * D_DIM + kc + g * 8], &Bs[(w * 32 + q * 8) * PBK]);
    }
  };

  STAGE(0, 0);
  __syncthreads();

  for (int t = 0; t < D_DIM / PBK; ++t) {
    const int cur = t & 1;
    if (t + 1 < D_DIM / PBK) STAGE(cur ^ 1, (t + 1) * PBK);

    const unsigned short* A = SB + cur * ((PTM + PTN) * PBK);
    const unsigned short* Bs = A + PTM * PBK;
    const int rsw = l16 & 7;
#pragma unroll
    for (int ks = 0; ks < 2; ++ks) {
      const int gphys = ((ks * 4 + q4) ^ rsw) * 8;
      bf16x8 afr[8], bfr[4];
#pragma unroll
      for (int m = 0; m < 8; ++m)
        afr[m] = *(const bf16x8*)&A[(wm + m * 16 + l16) * PBK + gphys];
#pragma unroll
      for (int n = 0; n < 4; ++n)
        bfr[n] = *(const bf16x8*)&Bs[(wn + n * 16 + l16) * PBK + gphys];
#pragma unroll
      for (int m = 0; m < 8; ++m)
#pragma unroll
        for (int n = 0; n < 4; ++n)
          acc[m][n] = __builtin_amdgcn_mfma_f32_16x16x32_bf16(afr[m], bfr[n], acc[m][n], 0, 0, 0);
    }
    __syncthreads();
  }

  const float* bias = (proj == 0) ? bq : (proj == 1) ? bk : (proj == 2) ? bv : ba;
  unsigned short* outp = (proj == 0) ? q_ws : (proj == 1) ? k_ws : (proj == 2) ? v_ws : g_ws;
  const bool do_relu = (proj <= 1);
  unsigned short* EP = &SB[w * 128 * 32];

#pragma unroll
  for (int p = 0; p < 2; ++p) {
#pragma unroll
    for (int half = 0; half < 2; ++half) {
      const int in_idx = p * 2 + half;
      const int nn = n0 + wn + in_idx * 16 + l16;
      const float bn = bias[nn];
#pragma unroll
      for (int m = 0; m < 8; ++m) {
#pragma unroll
        for (int vv = 0; vv < 4; ++vv) {
          float val = acc[m][in_idx][vv] + bn;
          if (do_relu) val = fmaxf(val, 0.f);
          EP[(m * 16 + q4 * 4 + vv) * 32 + half * 16 + l16] = f2bf(val);
        }
      }
    }
#pragma unroll
    for (int it = 0; it < 8; ++it) {
      const int row = it * 16 + (lane >> 2);
      const int ccol = (lane & 3) * 8;
      bf16x8 vdat = *(const bf16x8*)&EP[row * 32 + ccol];
      size_t gidx = (size_t)(m0 + wm + row) * D_DIM + (size_t)(n0 + wn + p * 32 + ccol);
      *(bf16x8*)&outp[gidx] = vdat;
    }
  }
}

// ---------------- prep: cum-factorized operands, segmented + bf16x8-vectorized -----
__global__ __launch_bounds__(512) void prep(
    const unsigned short* __restrict__ q, const unsigned short* __restrict__ k,
    const unsigned short* __restrict__ g,
    unsigned short* __restrict__ qt, unsigned short* __restrict__ kt,
    unsigned short* __restrict__ kh,
    float* __restrict__ Af, float* __restrict__ khs) {
  __shared__ float segp[8][512];   // 16 KB
  const int c = blockIdx.x, b = blockIdx.y;
  const int seg = threadIdx.x >> 6;
  const int t = threadIdx.x & 63;
  const int i0 = t * 8;
  const int r0 = seg * 8;
  const size_t t0 = (size_t)b * S_DIM + (size_t)c * CHUNK;
  const size_t cb = ((size_t)b * NCHUNK + c) * D_DIM;

  float sp[8];
#pragma unroll
  for (int j = 0; j < 8; ++j) sp[j] = 1.f;
  for (int r = 0; r < 8; ++r) {
    bf16x8 gv = *(const bf16x8*)&g[(t0 + r0 + r) * D_DIM + i0];
#pragma unroll
    for (int j = 0; j < 8; ++j)
      sp[j] *= 1.f / (1.f + __expf(-bf2f((unsigned short)gv[j])));
  }
  *(float4*)&segp[seg][i0] = *(float4*)&sp[0];
  *(float4*)&segp[seg][i0 + 4] = *(float4*)&sp[4];
  __syncthreads();

  float pre[8], tot[8];
#pragma unroll
  for (int j = 0; j < 8; ++j) { pre[j] = 1.f; tot[j] = 1.f; }
  for (int s2 = 0; s2 < 8; ++s2) {
    float4 v0 = *(const float4*)&segp[s2][i0];
    float4 v1 = *(const float4*)&segp[s2][i0 + 4];
    float v[8] = {v0.x, v0.y, v0.z, v0.w, v1.x, v1.y, v1.z, v1.w};
#pragma unroll
    for (int j = 0; j < 8; ++j) {
      tot[j] *= v[j];
      if (s2 < seg) pre[j] *= v[j];
    }
  }
  if (seg == 0) {
    float4 a0 = {tot[0], tot[1], tot[2], tot[3]};
    float4 a1 = {tot[4], tot[5], tot[6], tot[7]};
    *(float4*)&Af[cb + i0] = a0;
    *(float4*)&Af[cb + i0 + 4] = a1;
  }

  float cum[8], ssum[8];
#pragma unroll
  for (int j = 0; j < 8; ++j) { cum[j] = pre[j]; ssum[j] = 0.f; }
  for (int r = 0; r < 8; ++r) {
    size_t idx = (t0 + r0 + r) * D_DIM + i0;
    bf16x8 gv = *(const bf16x8*)&g[idx];
    bf16x8 qv8 = *(const bf16x8*)&q[idx];
    bf16x8 kv8 = *(const bf16x8*)&k[idx];
    bf16x8 oq, ok, okh;
#pragma unroll
    for (int j = 0; j < 8; ++j) {
      cum[j] *= 1.f / (1.f + __expf(-bf2f((unsigned short)gv[j])));
      float qv = bf2f((unsigned short)qv8[j]);
      float kv = bf2f((unsigned short)kv8[j]);
      oq[j] = (short)f2bf(qv * cum[j]);
      float inv = 1.f / cum[j];
      ok[j] = (short)f2bf(kv * inv);
      float khf = kv * (tot[j] * inv);
      okh[j] = (short)f2bf(khf);
      ssum[j] += khf;
    }
    *(bf16x8*)&qt[idx] = oq;
    *(bf16x8*)&kt[idx] = ok;
    *(bf16x8*)&kh[idx] = okh;
  }

  __syncthreads();
  *(float4*)&segp[seg][i0] = *(float4*)&ssum[0];
  *(float4*)&segp[seg][i0 + 4] = *(float4*)&ssum[4];
  __syncthreads();
  if (seg == 0) {
    float s[8];
#pragma unroll
    for (int j = 0; j < 8; ++j) s[j] = 0.f;
    for (int s2 = 0; s2 < 8; ++s2) {
      float4 v0 = *(const float4*)&segp[s2][i0];
      float4 v1 = *(const float4*)&segp[s2][i0 + 4];
      s[0] += v0.x; s[1] += v0.y; s[2] += v0.z; s[3] += v0.w;
      s[4] += v1.x; s[5] += v1.y; s[6] += v1.z; s[7] += v1.w;
    }
    float4 a0 = {s[0], s[1], s[2], s[3]};
    float4 a1 = {s[4], s[5], s[6], s[7]};
    *(float4*)&khs[cb + i0] = a0;
    *(float4*)&khs[cb + i0 + 4] = a1;
  }
}

// ---------------- per-chunk transpose [r][i] -> [i][r] (verified R3) ----------------
__global__ __launch_bounds__(256) void transpose_cd(
    const unsigned short* __restrict__ in, unsigned short* __restrict__ outT) {
  __shared__ unsigned short tile[CHUNK][264];
  const int c = blockIdx.x, b = blockIdx.y;
  const size_t base_in = ((size_t)b * S_DIM + (size_t)c * CHUNK) * D_DIM;
  const size_t base_out = ((size_t)b * NCHUNK + c) * (size_t)D_DIM * CHUNK;
  const int tid = threadIdx.x;
#pragma unroll
  for (int h = 0; h < 2; ++h) {
    if (h) __syncthreads();
#pragma unroll
    for (int it = 0; it < 8; ++it) {
      int flat = (it * 256 + tid) * 8;
      int row = flat >> 8;
      int col = flat & 255;
      *(uint4*)&tile[row][col] = *(const uint4*)&in[base_in + (size_t)row * D_DIM + h * 256 + col];
    }
    __syncthreads();
#pragma unroll
    for (int it = 0; it < 8; ++it) {
      int wq = it * 256 + tid;
      int i_loc = wq >> 3;
      int r0 = (wq & 7) * 8;
      ushort4 v0, v1;
      v0.x = tile[r0 + 0][i_loc]; v0.y = tile[r0 + 1][i_loc];
      v0.z = tile[r0 + 2][i_loc]; v0.w = tile[r0 + 3][i_loc];
      v1.x = tile[r0 + 4][i_loc]; v1.y = tile[r0 + 5][i_loc];
      v1.z = tile[r0 + 6][i_loc]; v1.w = tile[r0 + 7][i_loc];
      size_t o = base_out + (size_t)(h * 256 + i_loc) * CHUNK + r0;
      *(ushort4*)&outT[o] = v0;
      *(ushort4*)&outT[o + 4] = v1;
    }
  }
}

// ---------------- intra: P = mask(qt·kt^T), numI = P·V, FUSED denominators --------
// R8: denk folded in. z staged in LDS; q·z dot rides the existing qt fragment
// loads (each lane covers cols 32ks+8q4..+8 of its row; reduce over q4 lanes).
// Row-sums go through LDS (rsl) instead of a global rs buffer; invden written
// once, final. Saves a full qt re-read (33.5 MB) + a kernel launch.
__global__ __launch_bounds__(256) void intra(
    const unsigned short* __restrict__ qt, const unsigned short* kt,
    const unsigned short* __restrict__ VT, const float* __restrict__ zall,
    unsigned short* numI, float* __restrict__ invden) {
  __shared__ unsigned short P_lds[CHUNK][CHUNK + 8];
  __shared__ float zl[512];
  __shared__ float rsl[64];
  const int c = blockIdx.x, b = blockIdx.y;
  const size_t t0 = (size_t)b * S_DIM + (size_t)c * CHUNK;
  const size_t zb = ((size_t)b * NCHUNK + c) * D_DIM;
  const int lane = threadIdx.x & 63, w = threadIdx.x >> 6;
  const int l16 = lane & 15, q4 = lane >> 4;

  zl[threadIdx.x] = zall[zb + threadIdx.x];
  zl[threadIdx.x + 256] = zall[zb + threadIdx.x + 256];
  __syncthreads();   // zl ready before fused q.z accumulation

  f32x4 accP[4];
#pragma unroll
  for (int n = 0; n < 4; ++n) accP[n] = (f32x4){0.f, 0.f, 0.f, 0.f};
  float qdotz = 0.f;
#pragma unroll
  for (int ks = 0; ks < 16; ++ks) {
    bf16x8 afr = *(const bf16x8*)&qt[(t0 + 16 * w + l16) * D_DIM + 32 * ks + 8 * q4];
    const float* zp = &zl[32 * ks + 8 * q4];
#pragma unroll
    for (int j = 0; j < 8; ++j) qdotz = fmaf(bf2f((unsigned short)afr[j]), zp[j], qdotz);
#pragma unroll
    for (int n = 0; n < 4; ++n) {
      bf16x8 bfr = *(const bf16x8*)&kt[(t0 + 16 * n + l16) * D_DIM + 32 * ks + 8 * q4];
      accP[n] = __builtin_amdgcn_mfma_f32_16x16x32_bf16(afr, bfr, accP[n], 0, 0, 0);
    }
  }
  float rsum[4] = {0.f, 0.f, 0.f, 0.f};
#pragma unroll
  for (int n = 0; n < 4; ++n) {
    int m = 16 * n + l16;
#pragma unroll
    for (int vv = 0; vv < 4; ++vv) {
      int r = 16 * w + 4 * q4 + vv;
      float pv = (m <= r) ? accP[n][vv] : 0.f;
      rsum[vv] += pv;
      P_lds[r][m] = f2bf(pv);
    }
  }
#pragma unroll
  for (int msk = 1; msk < 16; msk <<= 1) {
#pragma unroll
    for (int vv = 0; vv < 4; ++vv) rsum[vv] += __shfl_xor(rsum[vv], msk, 64);
  }
  if (l16 == 0) {
#pragma unroll
    for (int vv = 0; vv < 4; ++vv) rsl[16 * w + 4 * q4 + vv] = rsum[vv];
  }
  __syncthreads();   // P_lds + rsl ready

  // finish denominators: reduce qdotz over the 4 q4-lanes of each row
  qdotz += __shfl_xor(qdotz, 16, 64);
  qdotz += __shfl_xor(qdotz, 32, 64);
  if (q4 == 0)
    invden[t0 + 16 * w + l16] = 1.f / (qdotz + rsl[16 * w + l16] + EPS_C);

  bf16x8 pa0 = *(const bf16x8*)&P_lds[16 * w + l16][8 * q4];
  bf16x8 pa1 = *(const bf16x8*)&P_lds[16 * w + l16][32 + 8 * q4];
  const size_t vtb = ((size_t)b * NCHUNK + c) * (size_t)D_DIM * CHUNK;
#pragma unroll 4
  for (int nt = 0; nt < 32; ++nt) {
    bf16x8 b0 = *(const bf16x8*)&VT[vtb + (size_t)(nt * 16 + l16) * CHUNK + 8 * q4];
    bf16x8 b1 = *(const bf16x8*)&VT[vtb + (size_t)(nt * 16 + l16) * CHUNK + 32 + 8 * q4];
    f32x4 acc = (f32x4){0.f, 0.f, 0.f, 0.f};
    acc = __builtin_amdgcn_mfma_f32_16x16x32_bf16(pa0, b0, acc, 0, 0, 0);
    acc = __builtin_amdgcn_mfma_f32_16x16x32_bf16(pa1, b1, acc, 0, 0, 0);
#pragma unroll
    for (int vv = 0; vv < 4; ++vv)
      numI[(t0 + 16 * w + 4 * q4 + vv) * D_DIM + nt * 16 + l16] = f2bf(acc[vv]);
  }
}

// ---------------- zscan: widened to 32 blocks (4 channel-groups x B) ---------------
__global__ __launch_bounds__(128) void zscan(
    const float* __restrict__ Af, const float* __restrict__ khs,
    float* __restrict__ zall, float* __restrict__ Pseg) {
  const int b = blockIdx.y;
  const int i = blockIdx.x * 128 + threadIdx.x;
  float z = 0.f, rp = 1.f;
  for (int c = 0; c < NCHUNK; ++c) {
    const size_t cb = ((size_t)b * NCHUNK + c) * D_DIM;
    zall[cb + i] = z;
    float af = Af[cb + i];
    z = fmaf(af, z, khs[cb + i]);
    rp *= af;
    if ((c & (CSEG - 1)) == CSEG - 1) {
      Pseg[((size_t)b * NSEG + (c / CSEG)) * D_DIM + i] = rp;
      rp = 1.f;
    }
  }
}

// ---------------- useg: J=64 blocks, 2 blocks/CU (R8 occupancy play) ---------------
// grid (NSEG, 8, B) = 512 blocks. 8 waves, each 64 i x 64 j state (acc[4][4],
// 64 f32/lane); VT double-buffered in LDS (16 KB); launch_bounds(512,4) caps
// VGPR at 128 -> 4 waves/SIMD for latency hiding (scan2 was latency-bound at 2).
__global__ __launch_bounds__(512, 4) void useg_k(
    const unsigned short* __restrict__ khT, const unsigned short* __restrict__ VT,
    const float* __restrict__ Af, unsigned short* __restrict__ U) {
  __shared__ unsigned short VTl[2][64 * 64];   // 16 KB dbuf, swizzled image
  const int s = blockIdx.x, jt = blockIdx.y, b = blockIdx.z;
  const int lane = threadIdx.x & 63, w = threadIdx.x >> 6;
  const int l16 = lane & 15, q4 = lane >> 4;
  const int j0 = jt * 64;
  const int iw = 64 * w;
  const int vrow = lane >> 3;
  const int vswz = (lane & 7) ^ (vrow & 7);

  f32x4 acc[4][4];
#pragma unroll
  for (int T = 0; T < 4; ++T)
#pragma unroll
    for (int h = 0; h < 4; ++h) acc[T][h] = (f32x4){0.f, 0.f, 0.f, 0.f};

  const size_t cb0 = ((size_t)b * NCHUNK + s * CSEG) * D_DIM;
  // prologue: stage VT(0) -- wave w covers rows [8w, 8w+8)
  GLOAD_LDS16(&VT[cb0 * CHUNK + (size_t)(j0 + 8 * w + vrow) * CHUNK + vswz * 8],
              &VTl[0][w * 512]);

  for (int cc = 0; cc < CSEG; ++cc) {
    const size_t cb = cb0 + (size_t)cc * D_DIM;
    const size_t ob = cb * CHUNK;
    __syncthreads();   // VT(cc) staged (barrier drains vmcnt)
    if (cc + 1 < CSEG) {
      GLOAD_LDS16(&VT[(cb + D_DIM) * CHUNK + (size_t)(j0 + 8 * w + vrow) * CHUNK + vswz * 8],
                  &VTl[(cc + 1) & 1][w * 512]);
    }
#pragma unroll
    for (int T = 0; T < 4; ++T) {
      float4 af = *(const float4*)&Af[cb + iw + 16 * T + 4 * q4];
#pragma unroll
      for (int h = 0; h < 4; ++h) {
        acc[T][h][0] *= af.x; acc[T][h][1] *= af.y; acc[T][h][2] *= af.z; acc[T][h][3] *= af.w;
      }
    }
    const unsigned short* Vb = VTl[cc & 1];
#pragma unroll
    for (int T = 0; T < 4; ++T) {
      bf16x8 a0 = *(const bf16x8*)&khT[ob + (size_t)(iw + 16 * T + l16) * CHUNK + 8 * q4];
      bf16x8 a1 = *(const bf16x8*)&khT[ob + (size_t)(iw + 16 * T + l16) * CHUNK + 32 + 8 * q4];
#pragma unroll
      for (int h = 0; h < 4; ++h) {
        const int jpos = 16 * h + l16;
        const int swz = jpos & 7;
        bf16x8 bv0 = *(const bf16x8*)&Vb[jpos * 64 + ((q4 ^ swz) * 8)];
        bf16x8 bv1 = *(const bf16x8*)&Vb[jpos * 64 + (((4 + q4) ^ swz) * 8)];
        acc[T][h] = __builtin_amdgcn_mfma_f32_16x16x32_bf16(a0, bv0, acc[T][h], 0, 0, 0);
        acc[T][h] = __builtin_amdgcn_mfma_f32_16x16x32_bf16(a1, bv1, acc[T][h], 0, 0, 0);
      }
    }
  }
  const size_t ub = ((size_t)b * NSEG + s) * D_DIM;
#pragma unroll
  for (int T = 0; T < 4; ++T)
#pragma unroll
    for (int h = 0; h < 4; ++h) {
      uint2 pk;
      pk.x = (uint32_t)f2bf(acc[T][h][0]) | ((uint32_t)f2bf(acc[T][h][1]) << 16);
      pk.y = (uint32_t)f2bf(acc[T][h][2]) | ((uint32_t)f2bf(acc[T][h][3]) << 16);
      *(uint2*)&U[(ub + j0 + 16 * h + l16) * (size_t)D_DIM + iw + 16 * T + 4 * q4] = pk;
    }
}

// ---------------- sscan: in-place prefix over segments: U[s] -> Sin[s] -------------
__global__ __launch_bounds__(256) void sscan(
    const float* __restrict__ Pseg, unsigned short* __restrict__ U) {
  const int b = blockIdx.y;
  const int flat = blockIdx.x * 256 + threadIdx.x;   // 0 .. 32767
  const int j = flat >> 6;
  const int i0 = (flat & 63) * 8;
  float acc[8];
#pragma unroll
  for (int t = 0; t < 8; ++t) acc[t] = 0.f;
  for (int s = 0; s < NSEG; ++s) {
    const size_t pb = ((size_t)b * NSEG + s) * D_DIM;
    unsigned short* up = &U[(pb + j) * (size_t)D_DIM + i0];
    uint4 u = *(const uint4*)up;
    float4 p0 = *(const float4*)&Pseg[pb + i0];
    float4 p1 = *(const float4*)&Pseg[pb + i0 + 4];
    float uv[8];
    uv[0] = bf2f((unsigned short)(u.x & 0xffff)); uv[1] = bf2f((unsigned short)(u.x >> 16));
    uv[2] = bf2f((unsigned short)(u.y & 0xffff)); uv[3] = bf2f((unsigned short)(u.y >> 16));
    uv[4] = bf2f((unsigned short)(u.z & 0xffff)); uv[5] = bf2f((unsigned short)(u.z >> 16));
    uv[6] = bf2f((unsigned short)(u.w & 0xffff)); uv[7] = bf2f((unsigned short)(u.w >> 16));
    uint4 o;
    o.x = (uint32_t)f2bf(acc[0]) | ((uint32_t)f2bf(acc[1]) << 16);
    o.y = (uint32_t)f2bf(acc[2]) | ((uint32_t)f2bf(acc[3]) << 16);
    o.z = (uint32_t)f2bf(acc[4]) | ((uint32_t)f2bf(acc[5]) << 16);
    o.w = (uint32_t)f2bf(acc[6]) | ((uint32_t)f2bf(acc[7]) << 16);
    *(uint4*)up = o;
    acc[0] = fmaf(p0.x, acc[0], uv[0]);
    acc[1] = fmaf(p0.y, acc[1], uv[1]);
    acc[2] = fmaf(p0.z, acc[2], uv[2]);
    acc[3] = fmaf(p0.w, acc[3], uv[3]);
    acc[4] = fmaf(p1.x, acc[4], uv[4]);
    acc[5] = fmaf(p1.y, acc[5], uv[5]);
    acc[6] = fmaf(p1.z, acc[6], uv[6]);
    acc[7] = fmaf(p1.w, acc[7], uv[7]);
  }
}

// ---------------- scan2: J=64 blocks, 2 blocks/CU (R8 occupancy play) --------------
// R5-R7 showed scan2 latency-bound at 2 waves/SIMD (volume cuts gave 0 gain, all
// pipes <22%). J=64: STj 66.5 KB + VTl 8 KB -> 2 blocks/CU; acc[4][4] (64 f32)
// + launch_bounds(512,4) -> VGPR<=128 -> 4 waves/SIMD. khT loaded at use point
// (frees 32 live VGPRs; 4-wave TLP hides the latency).
__global__ __launch_bounds__(512, 4) void scan2(
    const unsigned short* __restrict__ qt, const unsigned short* __restrict__ khT,
    const unsigned short* __restrict__ VT, const float* __restrict__ Af,
    const unsigned short* __restrict__ Sin,
    const unsigned short* __restrict__ numI, const float* __restrict__ invden,
    float* __restrict__ out) {
  __shared__ unsigned short STj[64][520];   // S^T: [j_local][i] bf16, 66.5 KB
  __shared__ unsigned short VTl[64 * 64];   // 8 KB, swizzled image
  const int s = blockIdx.x, jt = blockIdx.y, b = blockIdx.z;
  const int lane = threadIdx.x & 63, w = threadIdx.x >> 6;   // wave-uniform w
  const int l16 = lane & 15, q4 = lane >> 4;
  const int j0 = jt * 64;
  const int iw = 64 * w;          // state i-slice (unique per wave)
  const int rw = 16 * (w & 3);    // O row-tile
  const int jo = 32 * (w >> 2);   // O j-half (32 cols)
  const int vrow = lane >> 3;
  const int vswz = (lane & 7) ^ (vrow & 7);

  f32x4 acc[4][4];

  // initial state for this segment (precomputed by sscan)
  {
    const size_t pb = ((size_t)b * NSEG + s) * D_DIM;
#pragma unroll
    for (int T = 0; T < 4; ++T)
#pragma unroll
      for (int h = 0; h < 4; ++h) {
        uint2 uu = *(const uint2*)&Sin[(pb + j0 + 16 * h + l16) * (size_t)D_DIM + iw + 16 * T + 4 * q4];
        acc[T][h][0] = bf2f((unsigned short)(uu.x & 0xffff));
        acc[T][h][1] = bf2f((unsigned short)(uu.x >> 16));
        acc[T][h][2] = bf2f((unsigned short)(uu.y & 0xffff));
        acc[T][h][3] = bf2f((unsigned short)(uu.y >> 16));
      }
  }

  for (int cc = 0; cc < CSEG; ++cc) {
    const int c = s * CSEG + cc;
    const size_t cb = ((size_t)b * NCHUNK + c) * D_DIM;
    const size_t t0 = (size_t)b * S_DIM + (size_t)c * CHUNK;
    const size_t ob = cb * CHUNK;
    const bool upd = (cc != CSEG - 1);

    // early-issue VT -> LDS (consumed in state phase; barrier drains vmcnt)
    if (upd)
      GLOAD_LDS16(&VT[ob + (size_t)(j0 + 8 * w + vrow) * CHUNK + vswz * 8],
                  &VTl[w * 512]);

    // stage pre-update S^T to LDS (each wave its 64-i slice, full 64 j)
#pragma unroll
    for (int T = 0; T < 4; ++T)
#pragma unroll
      for (int h = 0; h < 4; ++h) {
        uint2 pk;
        pk.x = (uint32_t)f2bf(acc[T][h][0]) | ((uint32_t)f2bf(acc[T][h][1]) << 16);
        pk.y = (uint32_t)f2bf(acc[T][h][2]) | ((uint32_t)f2bf(acc[T][h][3]) << 16);
        *(uint2*)&STj[16 * h + l16][iw + 16 * T + 4 * q4] = pk;
      }
    __syncthreads();   // STj + VTl staged

    // O-compute: out rows [rw,rw+16) x cols [j0+jo, j0+jo+32)
    {
      f32x4 accO[2];
#pragma unroll
      for (int h = 0; h < 2; ++h) accO[h] = (f32x4){0.f, 0.f, 0.f, 0.f};
#pragma unroll
      for (int ks = 0; ks < 16; ++ks) {
        bf16x8 afr = *(const bf16x8*)&qt[(t0 + rw + l16) * D_DIM + 32 * ks + 8 * q4];
#pragma unroll
        for (int h = 0; h < 2; ++h) {
          bf16x8 bfr = *(const bf16x8*)&STj[jo + 16 * h + l16][32 * ks + 8 * q4];
          accO[h] = __builtin_amdgcn_mfma_f32_16x16x32_bf16(afr, bfr, accO[h], 0, 0, 0);
        }
      }
#pragma unroll
      for (int h = 0; h < 2; ++h)
#pragma unroll
        for (int vv = 0; vv < 4; ++vv) {
          size_t t = t0 + rw + 4 * q4 + vv;
          int j = j0 + jo + 16 * h + l16;
          float idv = invden[t];
          float nI = bf2f(numI[t * D_DIM + j]);
          out[t * D_DIM + j] = (accO[h][vv] + nI) * idv;
        }
    }

    // state update (skip on last chunk); khT loaded at use point
    if (upd) {
#pragma unroll
      for (int T = 0; T < 4; ++T) {
        float4 af = *(const float4*)&Af[cb + iw + 16 * T + 4 * q4];
#pragma unroll
        for (int h = 0; h < 4; ++h) {
          acc[T][h][0] *= af.x; acc[T][h][1] *= af.y; acc[T][h][2] *= af.z; acc[T][h][3] *= af.w;
        }
      }
#pragma unroll
      for (int T = 0; T < 4; ++T) {
        bf16x8 a0 = *(const bf16x8*)&khT[ob + (size_t)(iw + 16 * T + l16) * CHUNK + 8 * q4];
        bf16x8 a1 = *(const bf16x8*)&khT[ob + (size_t)(iw + 16 * T + l16) * CHUNK + 32 + 8 * q4];
#pragma unroll
        for (int h = 0; h < 4; ++h) {
          const int jpos = 16 * h + l16;
          const int swz = jpos & 7;
          bf16x8 bv0 = *(const bf16x8*)&VTl[jpos * 64 + ((q4 ^ swz) * 8)];
          bf16x8 bv1 = *(const bf16x8*)&VTl[jpos * 64 + (((4 + q4) ^ swz) * 8)];
          acc[T][h] = __builtin_amdgcn_mfma_f32_16x16x32_bf16(a0, bv0, acc[T][h], 0, 0, 0);
          acc[T][h] = __builtin_amdgcn_mfma_f32_16x16x32_bf16(a1, bv1, acc[T][h], 0, 0, 0);
        }
      }
    }
    __syncthreads();   // protect STj/VTl before next chunk's staging
  }
}

// ---------------- launch ----------------
extern "C" void kernel_launch(void* const* d_in, const int* in_sizes, int n_in,
                              void* d_out, int out_size, void* d_ws, size_t ws_size,
                              hipStream_t stream) {
  const float* x  = (const float*)d_in[0];
  const float* Wq = (const float*)d_in[1];
  const float* bq = (const float*)d_in[2];
  const float* Wk = (const float*)d_in[3];
  const float* bk = (const float*)d_in[4];
  const float* Wv = (const float*)d_in[5];
  const float* bv = (const float*)d_in[6];
  const float* Wa = (const float*)d_in[7];
  const float* ba = (const float*)d_in[8];
  float* out = (float*)d_out;

  // Workspace layout identical to R3/R4 (proven): ~172 MB.
  const size_t MD2 = (size_t)M_DIM * D_DIM * 2;
  uint8_t* w = (uint8_t*)d_ws;
  unsigned short* xb   = (unsigned short*)w; w += MD2;
  unsigned short* wb   = (unsigned short*)w; w += (size_t)4 * D_DIM * D_DIM * 2;  // 2 MB
  unsigned short* q_ws = (unsigned short*)w; w += MD2;
  unsigned short* k_ws = (unsigned short*)w; w += MD2;
  unsigned short* v_ws = (unsigned short*)w; w += MD2;
  unsigned short* g_ws = (unsigned short*)w; w += MD2;
  float* Af     = (float*)w; w += (size_t)B_DIM * NCHUNK * D_DIM * 4;  // 1 MB
  float* khs    = (float*)w; w += (size_t)B_DIM * NCHUNK * D_DIM * 4;  // 1 MB
  float* invden = (float*)w; w += (size_t)M_DIM * 4;                   // 128 KB

  unsigned short* qt   = xb;     // xb dead after proj_gemm
  unsigned short* kt   = q_ws;   // same-index overwrite inside prep
  unsigned short* kh   = k_ws;   // same-index overwrite inside prep
  unsigned short* VT   = g_ws;   // g dead after prep
  unsigned short* khT  = v_ws;   // v dead after its transpose
  unsigned short* numI = q_ws;   // kt dead after intra's P-phase
  unsigned short* U    = k_ws;   // kh dead after khT transpose; NSEG*B*512*512*2 == MD2 exactly
  float* zall = (float*)wb;                          // wb dead after proj; 1 MB
  float* Pseg = (float*)((uint8_t*)wb + (1 << 20));  // 128 KB

  cvt_f32_bf16<<<1024, 256, 0, stream>>>(x, xb, M_DIM * D_DIM / 4);
  cvt_f32_bf16<<<128, 256, 0, stream>>>(Wq, wb + 0 * D_DIM * D_DIM, D_DIM * D_DIM / 4);
  cvt_f32_bf16<<<128, 256, 0, stream>>>(Wk, wb + 1 * D_DIM * D_DIM, D_DIM * D_DIM / 4);
  cvt_f32_bf16<<<128, 256, 0, stream>>>(Wv, wb + 2 * D_DIM * D_DIM, D_DIM * D_DIM / 4);
  cvt_f32_bf16<<<128, 256, 0, stream>>>(Wa, wb + 3 * D_DIM * D_DIM, D_DIM * D_DIM / 4);

  proj_gemm<<<dim3(M_DIM / PTM, D_DIM / PTN, 4), 512, 0, stream>>>(
      xb, wb, bq, bk, bv, ba, q_ws, k_ws, v_ws, g_ws);

  prep<<<dim3(NCHUNK, B_DIM), 512, 0, stream>>>(q_ws, k_ws, g_ws, qt, kt, kh, Af, khs);
  transpose_cd<<<dim3(NCHUNK, B_DIM), 256, 0, stream>>>(v_ws, VT);
  transpose_cd<<<dim3(NCHUNK, B_DIM), 256, 0, stream>>>(kh, khT);
  zscan<<<dim3(4, B_DIM), 128, 0, stream>>>(Af, khs, zall, Pseg);
  intra<<<dim3(NCHUNK, B_DIM), 256, 0, stream>>>(qt, kt, VT, zall, numI, invden);
  useg_k<<<dim3(NSEG, 8, B_DIM), 512, 0, stream>>>(khT, VT, Af, U);
  sscan<<<dim3(128, B_DIM), 256, 0, stream>>>(Pseg, U);   // U -> Sin in place
  scan2<<<dim3(NSEG, 8, B_DIM), 512, 0, stream>>>(qt, khT, VT, Af, U, numI, invden, out);
}

// Round 9
// 496.473 us; speedup vs baseline: 1.0482x; 1.0482x over previous
//
#include <hip/hip_runtime.h>
#include <hip/hip_bf16.h>
#include <cstdint>
#include <cstddef>

#define D_DIM 512
#define B_DIM 8
#define S_DIM 4096
#define M_DIM (B_DIM * S_DIM)   // 32768 tokens
#define CHUNK 64
#define NCHUNK (S_DIM / CHUNK)  // 64 chunks per batch
#define NSEG 8
#define CSEG (NCHUNK / NSEG)    // 8 chunks per segment
#define EPS_C 1e-6f

typedef __attribute__((ext_vector_type(8))) short bf16x8;
typedef __attribute__((ext_vector_type(4))) float f32x4;

#define GLOAD_LDS16(src, dst)                                              \
  __builtin_amdgcn_global_load_lds(                                        \
      (const __attribute__((address_space(1))) void*)(src),                \
      (__attribute__((address_space(3))) void*)(dst), 16, 0, 0)

// lgkm-only barrier: LDS ordering without the compiler's vmcnt(0) drain.
// Global loads/stores stay in flight across it (waited only at use).
#define LGKM_BARRIER()                                                     \
  do {                                                                     \
    asm volatile("s_waitcnt lgkmcnt(0)" ::: "memory");                     \
    __builtin_amdgcn_s_barrier();                                          \
    __builtin_amdgcn_sched_barrier(0);                                     \
  } while (0)

__device__ __forceinline__ unsigned short f2bf(float f) {
  uint32_t u = __float_as_uint(f);
  u = (u + 0x7fffu + ((u >> 16) & 1u)) >> 16;   // RNE; inputs finite
  return (unsigned short)u;
}
__device__ __forceinline__ float bf2f(unsigned short s) { return __uint_as_float(((uint32_t)s) << 16); }

// ---------------- fp32 -> bf16 conversion ----------------
__global__ void cvt_f32_bf16(const float* __restrict__ in, unsigned short* __restrict__ out, int n4) {
  int i = blockIdx.x * blockDim.x + threadIdx.x;
  int stride = gridDim.x * blockDim.x;
  for (; i < n4; i += stride) {
    float4 f = ((const float4*)in)[i];
    ushort4 o;
    o.x = f2bf(f.x); o.y = f2bf(f.y); o.z = f2bf(f.z); o.w = f2bf(f.w);
    ((ushort4*)out)[i] = o;
  }
}

// ---------------- proj GEMM: 256x256 tile, BK=64, 2-phase single-barrier (R7) ------
#define PTM 256
#define PTN 256
#define PBK 64

__global__ __launch_bounds__(512, 2) void proj_gemm(
    const unsigned short* __restrict__ Xb,
    const unsigned short* __restrict__ Wb,
    const float* __restrict__ bq, const float* __restrict__ bk,
    const float* __restrict__ bv, const float* __restrict__ ba,
    unsigned short* __restrict__ q_ws, unsigned short* __restrict__ k_ws,
    unsigned short* __restrict__ v_ws, unsigned short* __restrict__ g_ws) {
  __shared__ unsigned short SB[2 * (PTM + PTN) * PBK];   // 128 KB

  const int proj = blockIdx.z;
  const unsigned short* W = Wb + (size_t)proj * D_DIM * D_DIM;
  const int m0 = blockIdx.x * PTM;
  const int n0 = blockIdx.y * PTN;
  const int lane = threadIdx.x & 63;
  const int w = threadIdx.x >> 6;
  const int l16 = lane & 15, q4 = lane >> 4;
  const int wm = (w >> 2) * 128;
  const int wn = (w & 3) * 64;

  f32x4 acc[8][4];
#pragma unroll
  for (int m = 0; m < 8; ++m)
#pragma unroll
    for (int n = 0; n < 4; ++n) acc[m][n] = (f32x4){0.f, 0.f, 0.f, 0.f};

  const int srow = lane >> 3;
  const int sg = lane & 7;

  auto STAGE = [&](int buf, int kc) {
    unsigned short* A = SB + buf * ((PTM + PTN) * PBK);
    unsigned short* Bs = A + PTM * PBK;
#pragma unroll
    for (int q = 0; q < 4; ++q) {
      const int row = w * 32 + q * 8 + srow;
      const int g = sg ^ (row & 7);
      GLOAD_LDS16(&Xb[(size_t)(m0 + row) * D_DIM + kc + g * 8], &A[(w * 32 + q * 8) * PBK]);
      GLOAD_LDS16(&W[(size_t)(n0 + row) * D_DIM + kc + g * 8], &Bs[(w * 32 + q * 8) * PBK]);
    }
  };

  STAGE(0, 0);
  __syncthreads();

  for (int t = 0; t < D_DIM / PBK; ++t) {
    const int cur = t & 1;
    if (t + 1 < D_DIM / PBK) STAGE(cur ^ 1, (t + 1) * PBK);

    const unsigned short* A = SB + cur * ((PTM + PTN) * PBK);
    const unsigned short* Bs = A + PTM * PBK;
    const int rsw = l16 & 7;
#pragma unroll
    for (int ks = 0; ks < 2; ++ks) {
      const int gphys = ((ks * 4 + q4) ^ rsw) * 8;
      bf16x8 afr[8], bfr[4];
#pragma unroll
      for (int m = 0; m < 8; ++m)
        afr[m] = *(const bf16x8*)&A[(wm + m * 16 + l16) * PBK + gphys];
#pragma unroll
      for (int n = 0; n < 4; ++n)
        bfr[n] = *(const bf16x8*)&Bs[(wn + n * 16 + l16) * PBK + gphys];
#pragma unroll
      for (int m = 0; m < 8; ++m)
#pragma unroll
        for (int n = 0; n < 4; ++n)
          acc[m][n] = __builtin_amdgcn_mfma_f32_16x16x32_bf16(afr[m], bfr[n], acc[m][n], 0, 0, 0);
    }
    __syncthreads();
  }

  const float* bias = (proj == 0) ? bq : (proj == 1) ? bk : (proj == 2) ? bv : ba;
  unsigned short* outp = (proj == 0) ? q_ws : (proj == 1) ? k_ws : (proj == 2) ? v_ws : g_ws;
  const bool do_relu = (proj <= 1);
  unsigned short* EP = &SB[w * 128 * 32];

#pragma unroll
  for (int p = 0; p < 2; ++p) {
#pragma unroll
    for (int half = 0; half < 2; ++half) {
      const int in_idx = p * 2 + half;
      const int nn = n0 + wn + in_idx * 16 + l16;
      const float bn = bias[nn];
#pragma unroll
      for (int m = 0; m < 8; ++m) {
#pragma unroll
        for (int vv = 0; vv < 4; ++vv) {
          float val = acc[m][in_idx][vv] + bn;
          if (do_relu) val = fmaxf(val, 0.f);
          EP[(m * 16 + q4 * 4 + vv) * 32 + half * 16 + l16] = f2bf(val);
        }
      }
    }
#pragma unroll
    for (int it = 0; it < 8; ++it) {
      const int row = it * 16 + (lane >> 2);
      const int ccol = (lane & 3) * 8;
      bf16x8 vdat = *(const bf16x8*)&EP[row * 32 + ccol];
      size_t gidx = (size_t)(m0 + wm + row) * D_DIM + (size_t)(n0 + wn + p * 32 + ccol);
      *(bf16x8*)&outp[gidx] = vdat;
    }
  }
}

// ---------------- prep: cum-factorized operands, segmented + bf16x8-vectorized -----
__global__ __launch_bounds__(512) void prep(
    const unsigned short* __restrict__ q, const unsigned short* __restrict__ k,
    const unsigned short* __restrict__ g,
    unsigned short* __restrict__ qt, unsigned short* __restrict__ kt,
    unsigned short* __restrict__ kh,
    float* __restrict__ Af, float* __restrict__ khs) {
  __shared__ float segp[8][512];   // 16 KB
  const int c = blockIdx.x, b = blockIdx.y;
  const int seg = threadIdx.x >> 6;
  const int t = threadIdx.x & 63;
  const int i0 = t * 8;
  const int r0 = seg * 8;
  const size_t t0 = (size_t)b * S_DIM + (size_t)c * CHUNK;
  const size_t cb = ((size_t)b * NCHUNK + c) * D_DIM;

  float sp[8];
#pragma unroll
  for (int j = 0; j < 8; ++j) sp[j] = 1.f;
  for (int r = 0; r < 8; ++r) {
    bf16x8 gv = *(const bf16x8*)&g[(t0 + r0 + r) * D_DIM + i0];
#pragma unroll
    for (int j = 0; j < 8; ++j)
      sp[j] *= 1.f / (1.f + __expf(-bf2f((unsigned short)gv[j])));
  }
  *(float4*)&segp[seg][i0] = *(float4*)&sp[0];
  *(float4*)&segp[seg][i0 + 4] = *(float4*)&sp[4];
  __syncthreads();

  float pre[8], tot[8];
#pragma unroll
  for (int j = 0; j < 8; ++j) { pre[j] = 1.f; tot[j] = 1.f; }
  for (int s2 = 0; s2 < 8; ++s2) {
    float4 v0 = *(const float4*)&segp[s2][i0];
    float4 v1 = *(const float4*)&segp[s2][i0 + 4];
    float v[8] = {v0.x, v0.y, v0.z, v0.w, v1.x, v1.y, v1.z, v1.w};
#pragma unroll
    for (int j = 0; j < 8; ++j) {
      tot[j] *= v[j];
      if (s2 < seg) pre[j] *= v[j];
    }
  }
  if (seg == 0) {
    float4 a0 = {tot[0], tot[1], tot[2], tot[3]};
    float4 a1 = {tot[4], tot[5], tot[6], tot[7]};
    *(float4*)&Af[cb + i0] = a0;
    *(float4*)&Af[cb + i0 + 4] = a1;
  }

  float cum[8], ssum[8];
#pragma unroll
  for (int j = 0; j < 8; ++j) { cum[j] = pre[j]; ssum[j] = 0.f; }
  for (int r = 0; r < 8; ++r) {
    size_t idx = (t0 + r0 + r) * D_DIM + i0;
    bf16x8 gv = *(const bf16x8*)&g[idx];
    bf16x8 qv8 = *(const bf16x8*)&q[idx];
    bf16x8 kv8 = *(const bf16x8*)&k[idx];
    bf16x8 oq, ok, okh;
#pragma unroll
    for (int j = 0; j < 8; ++j) {
      cum[j] *= 1.f / (1.f + __expf(-bf2f((unsigned short)gv[j])));
      float qv = bf2f((unsigned short)qv8[j]);
      float kv = bf2f((unsigned short)kv8[j]);
      oq[j] = (short)f2bf(qv * cum[j]);
      float inv = 1.f / cum[j];
      ok[j] = (short)f2bf(kv * inv);
      float khf = kv * (tot[j] * inv);
      okh[j] = (short)f2bf(khf);
      ssum[j] += khf;
    }
    *(bf16x8*)&qt[idx] = oq;
    *(bf16x8*)&kt[idx] = ok;
    *(bf16x8*)&kh[idx] = okh;
  }

  __syncthreads();
  *(float4*)&segp[seg][i0] = *(float4*)&ssum[0];
  *(float4*)&segp[seg][i0 + 4] = *(float4*)&ssum[4];
  __syncthreads();
  if (seg == 0) {
    float s[8];
#pragma unroll
    for (int j = 0; j < 8; ++j) s[j] = 0.f;
    for (int s2 = 0; s2 < 8; ++s2) {
      float4 v0 = *(const float4*)&segp[s2][i0];
      float4 v1 = *(const float4*)&segp[s2][i0 + 4];
      s[0] += v0.x; s[1] += v0.y; s[2] += v0.z; s[3] += v0.w;
      s[4] += v1.x; s[5] += v1.y; s[6] += v1.z; s[7] += v1.w;
    }
    float4 a0 = {s[0], s[1], s[2], s[3]};
    float4 a1 = {s[4], s[5], s[6], s[7]};
    *(float4*)&khs[cb + i0] = a0;
    *(float4*)&khs[cb + i0 + 4] = a1;
  }
}

// ---------------- per-chunk transpose [r][i] -> [i][r] (verified R3) ----------------
__global__ __launch_bounds__(256) void transpose_cd(
    const unsigned short* __restrict__ in, unsigned short* __restrict__ outT) {
  __shared__ unsigned short tile[CHUNK][264];
  const int c = blockIdx.x, b = blockIdx.y;
  const size_t base_in = ((size_t)b * S_DIM + (size_t)c * CHUNK) * D_DIM;
  const size_t base_out = ((size_t)b * NCHUNK + c) * (size_t)D_DIM * CHUNK;
  const int tid = threadIdx.x;
#pragma unroll
  for (int h = 0; h < 2; ++h) {
    if (h) __syncthreads();
#pragma unroll
    for (int it = 0; it < 8; ++it) {
      int flat = (it * 256 + tid) * 8;
      int row = flat >> 8;
      int col = flat & 255;
      *(uint4*)&tile[row][col] = *(const uint4*)&in[base_in + (size_t)row * D_DIM + h * 256 + col];
    }
    __syncthreads();
#pragma unroll
    for (int it = 0; it < 8; ++it) {
      int wq = it * 256 + tid;
      int i_loc = wq >> 3;
      int r0 = (wq & 7) * 8;
      ushort4 v0, v1;
      v0.x = tile[r0 + 0][i_loc]; v0.y = tile[r0 + 1][i_loc];
      v0.z = tile[r0 + 2][i_loc]; v0.w = tile[r0 + 3][i_loc];
      v1.x = tile[r0 + 4][i_loc]; v1.y = tile[r0 + 5][i_loc];
      v1.z = tile[r0 + 6][i_loc]; v1.w = tile[r0 + 7][i_loc];
      size_t o = base_out + (size_t)(h * 256 + i_loc) * CHUNK + r0;
      *(ushort4*)&outT[o] = v0;
      *(ushort4*)&outT[o + 4] = v1;
    }
  }
}

// ---------------- intra: P = mask(qt·kt^T), numI = P·V, FUSED denominators (R8) ----
__global__ __launch_bounds__(256) void intra(
    const unsigned short* __restrict__ qt, const unsigned short* kt,
    const unsigned short* __restrict__ VT, const float* __restrict__ zall,
    unsigned short* numI, float* __restrict__ invden) {
  __shared__ unsigned short P_lds[CHUNK][CHUNK + 8];
  __shared__ float zl[512];
  __shared__ float rsl[64];
  const int c = blockIdx.x, b = blockIdx.y;
  const size_t t0 = (size_t)b * S_DIM + (size_t)c * CHUNK;
  const size_t zb = ((size_t)b * NCHUNK + c) * D_DIM;
  const int lane = threadIdx.x & 63, w = threadIdx.x >> 6;
  const int l16 = lane & 15, q4 = lane >> 4;

  zl[threadIdx.x] = zall[zb + threadIdx.x];
  zl[threadIdx.x + 256] = zall[zb + threadIdx.x + 256];
  __syncthreads();   // zl ready before fused q.z accumulation

  f32x4 accP[4];
#pragma unroll
  for (int n = 0; n < 4; ++n) accP[n] = (f32x4){0.f, 0.f, 0.f, 0.f};
  float qdotz = 0.f;
#pragma unroll
  for (int ks = 0; ks < 16; ++ks) {
    bf16x8 afr = *(const bf16x8*)&qt[(t0 + 16 * w + l16) * D_DIM + 32 * ks + 8 * q4];
    const float* zp = &zl[32 * ks + 8 * q4];
#pragma unroll
    for (int j = 0; j < 8; ++j) qdotz = fmaf(bf2f((unsigned short)afr[j]), zp[j], qdotz);
#pragma unroll
    for (int n = 0; n < 4; ++n) {
      bf16x8 bfr = *(const bf16x8*)&kt[(t0 + 16 * n + l16) * D_DIM + 32 * ks + 8 * q4];
      accP[n] = __builtin_amdgcn_mfma_f32_16x16x32_bf16(afr, bfr, accP[n], 0, 0, 0);
    }
  }
  float rsum[4] = {0.f, 0.f, 0.f, 0.f};
#pragma unroll
  for (int n = 0; n < 4; ++n) {
    int m = 16 * n + l16;
#pragma unroll
    for (int vv = 0; vv < 4; ++vv) {
      int r = 16 * w + 4 * q4 + vv;
      float pv = (m <= r) ? accP[n][vv] : 0.f;
      rsum[vv] += pv;
      P_lds[r][m] = f2bf(pv);
    }
  }
#pragma unroll
  for (int msk = 1; msk < 16; msk <<= 1) {
#pragma unroll
    for (int vv = 0; vv < 4; ++vv) rsum[vv] += __shfl_xor(rsum[vv], msk, 64);
  }
  if (l16 == 0) {
#pragma unroll
    for (int vv = 0; vv < 4; ++vv) rsl[16 * w + 4 * q4 + vv] = rsum[vv];
  }
  __syncthreads();   // P_lds + rsl ready

  qdotz += __shfl_xor(qdotz, 16, 64);
  qdotz += __shfl_xor(qdotz, 32, 64);
  if (q4 == 0)
    invden[t0 + 16 * w + l16] = 1.f / (qdotz + rsl[16 * w + l16] + EPS_C);

  bf16x8 pa0 = *(const bf16x8*)&P_lds[16 * w + l16][8 * q4];
  bf16x8 pa1 = *(const bf16x8*)&P_lds[16 * w + l16][32 + 8 * q4];
  const size_t vtb = ((size_t)b * NCHUNK + c) * (size_t)D_DIM * CHUNK;
#pragma unroll 4
  for (int nt = 0; nt < 32; ++nt) {
    bf16x8 b0 = *(const bf16x8*)&VT[vtb + (size_t)(nt * 16 + l16) * CHUNK + 8 * q4];
    bf16x8 b1 = *(const bf16x8*)&VT[vtb + (size_t)(nt * 16 + l16) * CHUNK + 32 + 8 * q4];
    f32x4 acc = (f32x4){0.f, 0.f, 0.f, 0.f};
    acc = __builtin_amdgcn_mfma_f32_16x16x32_bf16(pa0, b0, acc, 0, 0, 0);
    acc = __builtin_amdgcn_mfma_f32_16x16x32_bf16(pa1, b1, acc, 0, 0, 0);
#pragma unroll
    for (int vv = 0; vv < 4; ++vv)
      numI[(t0 + 16 * w + 4 * q4 + vv) * D_DIM + nt * 16 + l16] = f2bf(acc[vv]);
  }
}

// ---------------- zscan: widened to 32 blocks (4 channel-groups x B) ---------------
__global__ __launch_bounds__(128) void zscan(
    const float* __restrict__ Af, const float* __restrict__ khs,
    float* __restrict__ zall, float* __restrict__ Pseg) {
  const int b = blockIdx.y;
  const int i = blockIdx.x * 128 + threadIdx.x;
  float z = 0.f, rp = 1.f;
  for (int c = 0; c < NCHUNK; ++c) {
    const size_t cb = ((size_t)b * NCHUNK + c) * D_DIM;
    zall[cb + i] = z;
    float af = Af[cb + i];
    z = fmaf(af, z, khs[cb + i]);
    rp *= af;
    if ((c & (CSEG - 1)) == CSEG - 1) {
      Pseg[((size_t)b * NSEG + (c / CSEG)) * D_DIM + i] = rp;
      rp = 1.f;
    }
  }
}

// ---------------- useg: J=128 (R5 shape), reg-staged VT dbuf, lgkm-only barriers ----
// Barriers no longer drain vmcnt -> khT/VT loads pipeline across chunks.
__global__ __launch_bounds__(512, 2) void useg_k(
    const unsigned short* __restrict__ khT, const unsigned short* __restrict__ VT,
    const float* __restrict__ Af, unsigned short* __restrict__ U) {
  __shared__ unsigned short VTl[2][128 * 64];   // 32 KB dbuf, swizzled image
  const int s = blockIdx.x, jt = blockIdx.y, b = blockIdx.z;
  const int lane = threadIdx.x & 63, w = threadIdx.x >> 6;
  const int l16 = lane & 15, q4 = lane >> 4;
  const int j0 = jt * 128;
  const int iw = 64 * w;           // i-slice per wave
  const int vrow = lane >> 3;      // 0..7 row within 8-row group
  const int vg = lane & 7;         // physical granule slot
  const int vgl = vg ^ vrow;       // logical source granule (swizzle)

  f32x4 acc[4][8];
#pragma unroll
  for (int T = 0; T < 4; ++T)
#pragma unroll
    for (int h = 0; h < 8; ++h) acc[T][h] = (f32x4){0.f, 0.f, 0.f, 0.f};

  const size_t cb0 = ((size_t)b * NCHUNK + s * CSEG) * D_DIM;
  bf16x8 vb0, vb1, a0[4], a1[4];
  {
    const size_t ob0 = cb0 * CHUNK;
    vb0 = *(const bf16x8*)&VT[ob0 + (size_t)(j0 + 16 * w + vrow) * CHUNK + vgl * 8];
    vb1 = *(const bf16x8*)&VT[ob0 + (size_t)(j0 + 16 * w + 8 + vrow) * CHUNK + vgl * 8];
#pragma unroll
    for (int T = 0; T < 4; ++T) {
      a0[T] = *(const bf16x8*)&khT[ob0 + (size_t)(iw + 16 * T + l16) * CHUNK + 8 * q4];
      a1[T] = *(const bf16x8*)&khT[ob0 + (size_t)(iw + 16 * T + l16) * CHUNK + 32 + 8 * q4];
    }
    *(bf16x8*)&VTl[0][(16 * w + vrow) * 64 + vg * 8] = vb0;
    *(bf16x8*)&VTl[0][(16 * w + 8 + vrow) * 64 + vg * 8] = vb1;
  }
  LGKM_BARRIER();   // VTl[0] staged

  for (int cc = 0; cc < CSEG; ++cc) {
    const size_t cb = cb0 + (size_t)cc * D_DIM;
    const size_t obn = (cb + D_DIM) * CHUNK;
    // early-issue next chunk's VT (consumed at end-of-iter ds_write)
    if (cc + 1 < CSEG) {
      vb0 = *(const bf16x8*)&VT[obn + (size_t)(j0 + 16 * w + vrow) * CHUNK + vgl * 8];
      vb1 = *(const bf16x8*)&VT[obn + (size_t)(j0 + 16 * w + 8 + vrow) * CHUNK + vgl * 8];
    }
#pragma unroll
    for (int T = 0; T < 4; ++T) {
      float4 af = *(const float4*)&Af[cb + iw + 16 * T + 4 * q4];
#pragma unroll
      for (int h = 0; h < 8; ++h) {
        acc[T][h][0] *= af.x; acc[T][h][1] *= af.y; acc[T][h][2] *= af.z; acc[T][h][3] *= af.w;
      }
    }
    const unsigned short* Vb = VTl[cc & 1];
#pragma unroll
    for (int h = 0; h < 8; ++h) {
      const int jpos = 16 * h + l16;
      const int swz = jpos & 7;
      bf16x8 bv0 = *(const bf16x8*)&Vb[jpos * 64 + ((q4 ^ swz) * 8)];
      bf16x8 bv1 = *(const bf16x8*)&Vb[jpos * 64 + (((4 + q4) ^ swz) * 8)];
#pragma unroll
      for (int T = 0; T < 4; ++T) {
        acc[T][h] = __builtin_amdgcn_mfma_f32_16x16x32_bf16(a0[T], bv0, acc[T][h], 0, 0, 0);
        acc[T][h] = __builtin_amdgcn_mfma_f32_16x16x32_bf16(a1[T], bv1, acc[T][h], 0, 0, 0);
      }
    }
    if (cc + 1 < CSEG) {
      // stage next VT into the other buffer; reload khT for next chunk
      unsigned short* Vn = VTl[(cc + 1) & 1];
      *(bf16x8*)&Vn[(16 * w + vrow) * 64 + vg * 8] = vb0;
      *(bf16x8*)&Vn[(16 * w + 8 + vrow) * 64 + vg * 8] = vb1;
#pragma unroll
      for (int T = 0; T < 4; ++T) {
        a0[T] = *(const bf16x8*)&khT[obn + (size_t)(iw + 16 * T + l16) * CHUNK + 8 * q4];
        a1[T] = *(const bf16x8*)&khT[obn + (size_t)(iw + 16 * T + l16) * CHUNK + 32 + 8 * q4];
      }
    }
    LGKM_BARRIER();   // next buf staged; this buf's reads done
  }
  const size_t ub = ((size_t)b * NSEG + s) * D_DIM;
#pragma unroll
  for (int T = 0; T < 4; ++T)
#pragma unroll
    for (int h = 0; h < 8; ++h) {
      uint2 pk;
      pk.x = (uint32_t)f2bf(acc[T][h][0]) | ((uint32_t)f2bf(acc[T][h][1]) << 16);
      pk.y = (uint32_t)f2bf(acc[T][h][2]) | ((uint32_t)f2bf(acc[T][h][3]) << 16);
      *(uint2*)&U[(ub + j0 + 16 * h + l16) * (size_t)D_DIM + iw + 16 * T + 4 * q4] = pk;
    }
}

// ---------------- sscan: in-place prefix over segments: U[s] -> Sin[s] -------------
__global__ __launch_bounds__(256) void sscan(
    const float* __restrict__ Pseg, unsigned short* __restrict__ U) {
  const int b = blockIdx.y;
  const int flat = blockIdx.x * 256 + threadIdx.x;   // 0 .. 32767
  const int j = flat >> 6;
  const int i0 = (flat & 63) * 8;
  float acc[8];
#pragma unroll
  for (int t = 0; t < 8; ++t) acc[t] = 0.f;
  for (int s = 0; s < NSEG; ++s) {
    const size_t pb = ((size_t)b * NSEG + s) * D_DIM;
    unsigned short* up = &U[(pb + j) * (size_t)D_DIM + i0];
    uint4 u = *(const uint4*)up;
    float4 p0 = *(const float4*)&Pseg[pb + i0];
    float4 p1 = *(const float4*)&Pseg[pb + i0 + 4];
    float uv[8];
    uv[0] = bf2f((unsigned short)(u.x & 0xffff)); uv[1] = bf2f((unsigned short)(u.x >> 16));
    uv[2] = bf2f((unsigned short)(u.y & 0xffff)); uv[3] = bf2f((unsigned short)(u.y >> 16));
    uv[4] = bf2f((unsigned short)(u.z & 0xffff)); uv[5] = bf2f((unsigned short)(u.z >> 16));
    uv[6] = bf2f((unsigned short)(u.w & 0xffff)); uv[7] = bf2f((unsigned short)(u.w >> 16));
    uint4 o;
    o.x = (uint32_t)f2bf(acc[0]) | ((uint32_t)f2bf(acc[1]) << 16);
    o.y = (uint32_t)f2bf(acc[2]) | ((uint32_t)f2bf(acc[3]) << 16);
    o.z = (uint32_t)f2bf(acc[4]) | ((uint32_t)f2bf(acc[5]) << 16);
    o.w = (uint32_t)f2bf(acc[6]) | ((uint32_t)f2bf(acc[7]) << 16);
    *(uint4*)up = o;
    acc[0] = fmaf(p0.x, acc[0], uv[0]);
    acc[1] = fmaf(p0.y, acc[1], uv[1]);
    acc[2] = fmaf(p0.z, acc[2], uv[2]);
    acc[3] = fmaf(p0.w, acc[3], uv[3]);
    acc[4] = fmaf(p1.x, acc[4], uv[4]);
    acc[5] = fmaf(p1.y, acc[5], uv[5]);
    acc[6] = fmaf(p1.z, acc[6], uv[6]);
    acc[7] = fmaf(p1.w, acc[7], uv[7]);
  }
}

// ---------------- scan2: J=128 (R5 shape), reg-staged VT, lgkm-only barriers -------
// R8 diagnosis: at J=128 scan2 is serial-latency-bound; the compiler's
// vmcnt(0) drain at each __syncthreads serialized 50+ global ops (qt/numI
// loads, out stores) into every chunk. Reg-staged VT removes the need for
// any vmcnt at barriers; global traffic now pipelines across chunks.
__global__ __launch_bounds__(512, 2) void scan2(
    const unsigned short* __restrict__ qt, const unsigned short* __restrict__ khT,
    const unsigned short* __restrict__ VT, const float* __restrict__ Af,
    const unsigned short* __restrict__ Sin,
    const unsigned short* __restrict__ numI, const float* __restrict__ invden,
    float* __restrict__ out) {
  __shared__ unsigned short STj[128][520];   // S^T: [j_local][i] bf16, 133 KB
  __shared__ unsigned short VTl[128 * 64];   // 16 KB, swizzled image
  const int s = blockIdx.x, jt = blockIdx.y, b = blockIdx.z;
  const int lane = threadIdx.x & 63, w = threadIdx.x >> 6;   // wave-uniform w
  const int l16 = lane & 15, q4 = lane >> 4;
  const int j0 = jt * 128;
  const int iw = 64 * w;          // state i-slice (unique per wave)
  const int rw = 16 * (w & 3);    // O row-tile
  const int jo = 64 * (w >> 2);   // O j-half
  const int vrow = lane >> 3;
  const int vg = lane & 7;
  const int vgl = vg ^ vrow;

  f32x4 acc[4][8];

  // initial state for this segment (precomputed by sscan)
  {
    const size_t pb = ((size_t)b * NSEG + s) * D_DIM;
#pragma unroll
    for (int T = 0; T < 4; ++T)
#pragma unroll
      for (int h = 0; h < 8; ++h) {
        uint2 uu = *(const uint2*)&Sin[(pb + j0 + 16 * h + l16) * (size_t)D_DIM + iw + 16 * T + 4 * q4];
        acc[T][h][0] = bf2f((unsigned short)(uu.x & 0xffff));
        acc[T][h][1] = bf2f((unsigned short)(uu.x >> 16));
        acc[T][h][2] = bf2f((unsigned short)(uu.y & 0xffff));
        acc[T][h][3] = bf2f((unsigned short)(uu.y >> 16));
      }
  }

  // prologue: early-issue VT(0) + khT(0) (chunk 0 is always an update chunk)
  bf16x8 vb0, vb1, a0[4], a1[4];
  {
    const size_t ob0 = ((size_t)b * NCHUNK + s * CSEG) * D_DIM * CHUNK;
    vb0 = *(const bf16x8*)&VT[ob0 + (size_t)(j0 + 16 * w + vrow) * CHUNK + vgl * 8];
    vb1 = *(const bf16x8*)&VT[ob0 + (size_t)(j0 + 16 * w + 8 + vrow) * CHUNK + vgl * 8];
#pragma unroll
    for (int T = 0; T < 4; ++T) {
      a0[T] = *(const bf16x8*)&khT[ob0 + (size_t)(iw + 16 * T + l16) * CHUNK + 8 * q4];
      a1[T] = *(const bf16x8*)&khT[ob0 + (size_t)(iw + 16 * T + l16) * CHUNK + 32 + 8 * q4];
    }
  }

  for (int cc = 0; cc < CSEG; ++cc) {
    const int c = s * CSEG + cc;
    const size_t cb = ((size_t)b * NCHUNK + c) * D_DIM;
    const size_t t0 = (size_t)b * S_DIM + (size_t)c * CHUNK;
    const size_t ob = cb * CHUNK;
    const bool upd = (cc != CSEG - 1);

    // stage pre-update S^T to LDS (each wave its i-slice, full j)
#pragma unroll
    for (int T = 0; T < 4; ++T)
#pragma unroll
      for (int h = 0; h < 8; ++h) {
        uint2 pk;
        pk.x = (uint32_t)f2bf(acc[T][h][0]) | ((uint32_t)f2bf(acc[T][h][1]) << 16);
        pk.y = (uint32_t)f2bf(acc[T][h][2]) | ((uint32_t)f2bf(acc[T][h][3]) << 16);
        *(uint2*)&STj[16 * h + l16][iw + 16 * T + 4 * q4] = pk;
      }
    // stage VT(cc) image (regs -> LDS); compiler waits vmcnt for vb here only
    if (upd) {
      *(bf16x8*)&VTl[(16 * w + vrow) * 64 + vg * 8] = vb0;
      *(bf16x8*)&VTl[(16 * w + 8 + vrow) * 64 + vg * 8] = vb1;
    }
    LGKM_BARRIER();   // STj + VTl staged; NO vmcnt drain

    // early-issue VT for chunk cc+1 (consumed next chunk, full-chunk latency)
    if (cc < CSEG - 2) {
      const size_t obn = ob + (size_t)D_DIM * CHUNK;
      vb0 = *(const bf16x8*)&VT[obn + (size_t)(j0 + 16 * w + vrow) * CHUNK + vgl * 8];
      vb1 = *(const bf16x8*)&VT[obn + (size_t)(j0 + 16 * w + 8 + vrow) * CHUNK + vgl * 8];
    }

    // O-compute: out rows [rw,rw+16) x cols [j0+jo, j0+jo+64)
    {
      f32x4 accO[4];
#pragma unroll
      for (int h = 0; h < 4; ++h) accO[h] = (f32x4){0.f, 0.f, 0.f, 0.f};
#pragma unroll
      for (int ks = 0; ks < 16; ++ks) {
        bf16x8 afr = *(const bf16x8*)&qt[(t0 + rw + l16) * D_DIM + 32 * ks + 8 * q4];
#pragma unroll
        for (int h = 0; h < 4; ++h) {
          bf16x8 bfr = *(const bf16x8*)&STj[jo + 16 * h + l16][32 * ks + 8 * q4];
          accO[h] = __builtin_amdgcn_mfma_f32_16x16x32_bf16(afr, bfr, accO[h], 0, 0, 0);
        }
      }
#pragma unroll
      for (int h = 0; h < 4; ++h)
#pragma unroll
        for (int vv = 0; vv < 4; ++vv) {
          size_t t = t0 + rw + 4 * q4 + vv;
          int j = j0 + jo + 16 * h + l16;
          float idv = invden[t];
          float nI = bf2f(numI[t * D_DIM + j]);
          out[t * D_DIM + j] = (accO[h][vv] + nI) * idv;
        }
    }

    // state update (skip on last chunk)
    if (upd) {
#pragma unroll
      for (int T = 0; T < 4; ++T) {
        float4 af = *(const float4*)&Af[cb + iw + 16 * T + 4 * q4];
#pragma unroll
        for (int h = 0; h < 8; ++h) {
          acc[T][h][0] *= af.x; acc[T][h][1] *= af.y; acc[T][h][2] *= af.z; acc[T][h][3] *= af.w;
        }
      }
#pragma unroll
      for (int h = 0; h < 8; ++h) {
        const int jpos = 16 * h + l16;
        const int swz = jpos & 7;
        bf16x8 bv0 = *(const bf16x8*)&VTl[jpos * 64 + ((q4 ^ swz) * 8)];
        bf16x8 bv1 = *(const bf16x8*)&VTl[jpos * 64 + (((4 + q4) ^ swz) * 8)];
#pragma unroll
        for (int T = 0; T < 4; ++T) {
          acc[T][h] = __builtin_amdgcn_mfma_f32_16x16x32_bf16(a0[T], bv0, acc[T][h], 0, 0, 0);
          acc[T][h] = __builtin_amdgcn_mfma_f32_16x16x32_bf16(a1[T], bv1, acc[T][h], 0, 0, 0);
        }
      }
    }
    // early-issue khT for chunk cc+1 (after last use of a0/a1)
    if (cc < CSEG - 2) {
      const size_t obn = ob + (size_t)D_DIM * CHUNK;
#pragma unroll
      for (int T = 0; T < 4; ++T) {
        a0[T] = *(const bf16x8*)&khT[obn + (size_t)(iw + 16 * T + l16) * CHUNK + 8 * q4];
        a1[T] = *(const bf16x8*)&khT[obn + (size_t)(iw + 16 * T + l16) * CHUNK + 32 + 8 * q4];
      }
    }
    LGKM_BARRIER();   // STj/VTl reads done before next chunk's staging
  }
}

// ---------------- launch ----------------
extern "C" void kernel_launch(void* const* d_in, const int* in_sizes, int n_in,
                              void* d_out, int out_size, void* d_ws, size_t ws_size,
                              hipStream_t stream) {
  const float* x  = (const float*)d_in[0];
  const float* Wq = (const float*)d_in[1];
  const float* bq = (const float*)d_in[2];
  const float* Wk = (const float*)d_in[3];
  const float* bk = (const float*)d_in[4];
  const float* Wv = (const float*)d_in[5];
  const float* bv = (const float*)d_in[6];
  const float* Wa = (const float*)d_in[7];
  const float* ba = (const float*)d_in[8];
  float* out = (float*)d_out;

  // Workspace layout identical to R3/R4 (proven): ~172 MB.
  const size_t MD2 = (size_t)M_DIM * D_DIM * 2;
  uint8_t* w = (uint8_t*)d_ws;
  unsigned short* xb   = (unsigned short*)w; w += MD2;
  unsigned short* wb   = (unsigned short*)w; w += (size_t)4 * D_DIM * D_DIM * 2;  // 2 MB
  unsigned short* q_ws = (unsigned short*)w; w += MD2;
  unsigned short* k_ws = (unsigned short*)w; w += MD2;
  unsigned short* v_ws = (unsigned short*)w; w += MD2;
  unsigned short* g_ws = (unsigned short*)w; w += MD2;
  float* Af     = (float*)w; w += (size_t)B_DIM * NCHUNK * D_DIM * 4;  // 1 MB
  float* khs    = (float*)w; w += (size_t)B_DIM * NCHUNK * D_DIM * 4;  // 1 MB
  float* invden = (float*)w; w += (size_t)M_DIM * 4;                   // 128 KB

  unsigned short* qt   = xb;     // xb dead after proj_gemm
  unsigned short* kt   = q_ws;   // same-index overwrite inside prep
  unsigned short* kh   = k_ws;   // same-index overwrite inside prep
  unsigned short* VT   = g_ws;   // g dead after prep
  unsigned short* khT  = v_ws;   // v dead after its transpose
  unsigned short* numI = q_ws;   // kt dead after intra's P-phase
  unsigned short* U    = k_ws;   // kh dead after khT transpose; NSEG*B*512*512*2 == MD2 exactly
  float* zall = (float*)wb;                          // wb dead after proj; 1 MB
  float* Pseg = (float*)((uint8_t*)wb + (1 << 20));  // 128 KB

  cvt_f32_bf16<<<1024, 256, 0, stream>>>(x, xb, M_DIM * D_DIM / 4);
  cvt_f32_bf16<<<128, 256, 0, stream>>>(Wq, wb + 0 * D_DIM * D_DIM, D_DIM * D_DIM / 4);
  cvt_f32_bf16<<<128, 256, 0, stream>>>(Wk, wb + 1 * D_DIM * D_DIM, D_DIM * D_DIM / 4);
  cvt_f32_bf16<<<128, 256, 0, stream>>>(Wv, wb + 2 * D_DIM * D_DIM, D_DIM * D_DIM / 4);
  cvt_f32_bf16<<<128, 256, 0, stream>>>(Wa, wb + 3 * D_DIM * D_DIM, D_DIM * D_DIM / 4);

  proj_gemm<<<dim3(M_DIM / PTM, D_DIM / PTN, 4), 512, 0, stream>>>(
      xb, wb, bq, bk, bv, ba, q_ws, k_ws, v_ws, g_ws);

  prep<<<dim3(NCHUNK, B_DIM), 512, 0, stream>>>(q_ws, k_ws, g_ws, qt, kt, kh, Af, khs);
  transpose_cd<<<dim3(NCHUNK, B_DIM), 256, 0, stream>>>(v_ws, VT);
  transpose_cd<<<dim3(NCHUNK, B_DIM), 256, 0, stream>>>(kh, khT);
  zscan<<<dim3(4, B_DIM), 128, 0, stream>>>(Af, khs, zall, Pseg);
  intra<<<dim3(NCHUNK, B_DIM), 256, 0, stream>>>(qt, kt, VT, zall, numI, invden);
  useg_k<<<dim3(NSEG, 4, B_DIM), 512, 0, stream>>>(khT, VT, Af, U);
  sscan<<<dim3(128, B_DIM), 256, 0, stream>>>(Pseg, U);   // U -> Sin in place
  scan2<<<dim3(NSEG, 4, B_DIM), 512, 0, stream>>>(qt, khT, VT, Af, U, numI, invden, out);
}